// Round 10
// baseline (246.302 us; speedup 1.0000x reference)
//
#include <hip/hip_runtime.h>

typedef unsigned short u16;
typedef unsigned int u32;

#define TOKENS 4096   // B*T
#define HDIM 1024
#define IDIM 4096
#define NHEADS 4
#define NKEYS 64
#define TOPK 8
#define QDIM 512      // 2 * NHEADS * 64

typedef __bf16 bf16x8 __attribute__((ext_vector_type(8)));
typedef float  f32x4  __attribute__((ext_vector_type(4)));
typedef u16    u16x8  __attribute__((ext_vector_type(8)));
typedef u16    u16x4  __attribute__((ext_vector_type(4)));
typedef u32    u32x4  __attribute__((ext_vector_type(4)));

__device__ __forceinline__ u16 f2bf(float f) {
    u32 u = __float_as_uint(f);
    u += 0x7fffu + ((u >> 16) & 1u);   // RNE
    return (u16)(u >> 16);
}
__device__ __forceinline__ float bf2f(u16 h) { return __uint_as_float(((u32)h) << 16); }

// ---- fused fp32->bf16 / fp32->fp8 conversion over all tensors ----
#define H_N4   1048576   // TOKENS*HDIM/4   (hi+lo)
#define WUP_N4 1048576
#define WDN_N4 1048576
#define DE_N4  1048576
#define UE_N4  1048576
#define CVT_TOT (H_N4 + WUP_N4 + WDN_N4 + DE_N4 + UE_N4)

__device__ __forceinline__ void cvt1(const float* in, u16* hi, u16* lo, int i) {
    float4 v = reinterpret_cast<const float4*>(in)[i];
    float vf[4] = {v.x, v.y, v.z, v.w};
    ushort4 h;
    u16 hh[4];
#pragma unroll
    for (int j = 0; j < 4; j++) hh[j] = f2bf(vf[j]);
    h.x = hh[0]; h.y = hh[1]; h.z = hh[2]; h.w = hh[3];
    reinterpret_cast<ushort4*>(hi)[i] = h;
    if (lo) {
        ushort4 l4;
        u16 ll[4];
#pragma unroll
        for (int j = 0; j < 4; j++) ll[j] = f2bf(vf[j] - bf2f(hh[j]));
        l4.x = ll[0]; l4.y = ll[1]; l4.z = ll[2]; l4.w = ll[3];
        reinterpret_cast<ushort4*>(lo)[i] = l4;
    }
}

__device__ __forceinline__ void cvt1_f8(const float* in, u32* out8, int i) {
    float4 v = reinterpret_cast<const float4*>(in)[i];
    u32 w = __builtin_amdgcn_cvt_pk_fp8_f32(v.x, v.y, 0u, false);
    w = __builtin_amdgcn_cvt_pk_fp8_f32(v.z, v.w, w, true);
    out8[i] = w;
}

__global__ __launch_bounds__(256) void cvt_all(
    const float* __restrict__ hidden, const float* __restrict__ W_up,
    const float* __restrict__ W_down, const float* __restrict__ de,
    const float* __restrict__ ue,
    u16* __restrict__ hid_hi, u16* __restrict__ hid_lo,
    u16* __restrict__ wup, u16* __restrict__ wdn,
    u32* __restrict__ de_f8, u32* __restrict__ ue_f8) {
    int i = blockIdx.x * 256 + threadIdx.x;
    if (i >= CVT_TOT) return;
    if (i < H_N4) { cvt1(hidden, hid_hi, hid_lo, i); return; }
    i -= H_N4;
    if (i < WUP_N4) { cvt1(W_up, wup, nullptr, i); return; }
    i -= WUP_N4;
    if (i < WDN_N4) { cvt1(W_down, wdn, nullptr, i); return; }
    i -= WDN_N4;
    if (i < DE_N4) { cvt1_f8(de, de_f8, i); return; }
    i -= DE_N4;
    cvt1_f8(ue, ue_f8, i);
}

// Weff[(p*4+h)*64+k][d] = sum_n keys[h][k][p][n] * Wq[p*256+h*64+n][d],
// fp32 accumulate, split hi/lo bf16 output.
__global__ __launch_bounds__(256) void weff_kernel(
    const float* __restrict__ keys, const float* __restrict__ Wq,
    u16* __restrict__ weff_hi, u16* __restrict__ weff_lo) {
    __shared__ float kk[64][65];
    __shared__ float wq_s[64][128];

    const int g = blockIdx.x >> 3, ds = blockIdx.x & 7;
    const int p = g >> 2, h = g & 3;
    const int d0 = ds * 128;
    const int t = threadIdx.x;
    const int base = p * 256 + h * 64;

    {
        int k = t >> 2, part = t & 3;
        const float* krow = keys + (((size_t)(h * NKEYS + k) * 2 + p) * 64);
#pragma unroll
        for (int j = 0; j < 4; j++) {
            int n0 = part * 16 + j * 4;
            float4 v = *reinterpret_cast<const float4*>(krow + n0);
            kk[k][n0 + 0] = v.x; kk[k][n0 + 1] = v.y;
            kk[k][n0 + 2] = v.z; kk[k][n0 + 3] = v.w;
        }
    }
    {
        int n = t >> 2, dpart = t & 3;
        const float* wrow = Wq + (size_t)(base + n) * HDIM + d0;
#pragma unroll
        for (int j = 0; j < 8; j++) {
            int dd = dpart * 32 + j * 4;
            float4 v = *reinterpret_cast<const float4*>(wrow + dd);
            *reinterpret_cast<float4*>(&wq_s[n][dd]) = v;
        }
    }
    __syncthreads();

    const int k = t & 63, dq = t >> 6;
    float acc[32];
#pragma unroll
    for (int i = 0; i < 32; i++) acc[i] = 0.f;
    for (int n = 0; n < 64; n++) {
        float kv = kk[k][n];
        const float4* wrow = reinterpret_cast<const float4*>(&wq_s[n][dq * 32]);
#pragma unroll
        for (int j = 0; j < 8; j++) {
            float4 w4 = wrow[j];
            acc[j * 4 + 0] += kv * w4.x; acc[j * 4 + 1] += kv * w4.y;
            acc[j * 4 + 2] += kv * w4.z; acc[j * 4 + 3] += kv * w4.w;
        }
    }
    size_t ro = (size_t)(g * 64 + k) * HDIM + d0 + dq * 32;
#pragma unroll
    for (int j = 0; j < 8; j++) {
        ushort4 hh, ll;
        u16 hv[4], lv[4];
#pragma unroll
        for (int i = 0; i < 4; i++) {
            float a = acc[j * 4 + i];
            hv[i] = f2bf(a);
            lv[i] = f2bf(a - bf2f(hv[i]));
        }
        hh.x = hv[0]; hh.y = hv[1]; hh.z = hv[2]; hh.w = hv[3];
        ll.x = lv[0]; ll.y = lv[1]; ll.z = lv[2]; ll.w = lv[3];
        *reinterpret_cast<ushort4*>(weff_hi + ro + j * 4) = hh;
        *reinterpret_cast<ushort4*>(weff_lo + ro + j * 4) = ll;
    }
}

// out += p1 + p2 + p3 (after all 4 K-chunks of down proj)
__global__ __launch_bounds__(256) void reduce_add3(float* __restrict__ out,
                                                   const float* __restrict__ p1,
                                                   const float* __restrict__ p2,
                                                   const float* __restrict__ p3, int n4) {
    int i = blockIdx.x * 256 + threadIdx.x;
    if (i >= n4) return;
    float4 a = reinterpret_cast<const float4*>(out)[i];
    float4 b = reinterpret_cast<const float4*>(p1)[i];
    float4 c = reinterpret_cast<const float4*>(p2)[i];
    float4 d = reinterpret_cast<const float4*>(p3)[i];
    a.x += b.x + c.x + d.x; a.y += b.y + c.y + d.y;
    a.z += b.z + c.z + d.z; a.w += b.w + c.w + d.w;
    reinterpret_cast<float4*>(out)[i] = a;
}

__device__ __forceinline__ void gload16(const void* g, void* s) {
    auto gp = reinterpret_cast<const __attribute__((address_space(1))) u32*>(
        reinterpret_cast<uintptr_t>(g));
    auto sp = reinterpret_cast<__attribute__((address_space(3))) u32*>(
        reinterpret_cast<uintptr_t>(s));
    __builtin_amdgcn_global_load_lds(gp, sp, 16, 0, 0);
}

#define BK 32

// ---- 2-phase template (kept for the sim projection) ----
// LDS rows of 64B; swizzle slot ^= (row>>1)&3 (verified: 0 bank conflicts).
__device__ __forceinline__ int swz(int a) { return a ^ (((a >> 7) & 3) << 4); }

template <int ROWS, int THREADS>
__device__ __forceinline__ void stage_tile(const u16* g, size_t krow_b, size_t kb0,
                                           u16* s, int t) {
#pragma unroll
    for (int rnd = 0; rnd < ROWS * 64 / (THREADS * 16); rnd++) {
        int o = t * 16 + rnd * THREADS * 16;
        int os = swz(o);
        int row = o >> 6, kb = os & 63;
        gload16((const char*)g + (size_t)row * krow_b + kb0 + kb, (char*)s + o);
    }
}

template <int EPI, int TBM, int TBN, int WVM, int WVN, bool SPLIT>
__global__ __launch_bounds__(WVM * WVN * 64) void gemm_bt(
    const u16* __restrict__ A, const u16* __restrict__ Alo,
    const u16* __restrict__ B, const u16* __restrict__ Blo,
    void* __restrict__ Cout, int M, int N, int K) {
    constexpr int THREADS = WVM * WVN * 64;
    constexpr int NS = SPLIT ? 2 : 1;
    constexpr int WM = TBM / WVM, WN = TBN / WVN;
    constexpr int FM = WM / 16, FN = WN / 16;
    constexpr int ASZ = NS * TBM * BK;
    constexpr int BSZ = NS * TBN * BK;
    __shared__ u16 As[2][ASZ];
    __shared__ u16 Bs[2][BSZ];
    const int t = threadIdx.x;
    const int lane = t & 63;
    const int wave = t >> 6;
    const int wr = wave / WVN, wc = wave % WVN;
    const int m0 = blockIdx.y * TBM;
    const int n0 = blockIdx.x * TBN;

    f32x4 acc[FM][FN];
#pragma unroll
    for (int i = 0; i < FM; i++)
#pragma unroll
        for (int j = 0; j < FN; j++) acc[i][j] = (f32x4){0.f, 0.f, 0.f, 0.f};

    const size_t krow = (size_t)K * 2;
    const int ro = lane & 15;
    const int ko = (lane >> 4) * 16;

    const u16* Ab = A + (size_t)m0 * K;
    const u16* Bb = B + (size_t)n0 * K;
    const u16* Alb = SPLIT ? Alo + (size_t)m0 * K : nullptr;
    const u16* Blb = SPLIT ? Blo + (size_t)n0 * K : nullptr;

    auto stage_all = [&](int b, int k0) {
        size_t kb0 = (size_t)k0 * 2;
        stage_tile<TBM, THREADS>(Ab, krow, kb0, As[b], t);
        stage_tile<TBN, THREADS>(Bb, krow, kb0, Bs[b], t);
        if (SPLIT) {
            stage_tile<TBM, THREADS>(Alb, krow, kb0, As[b] + TBM * BK, t);
            stage_tile<TBN, THREADS>(Blb, krow, kb0, Bs[b] + TBN * BK, t);
        }
    };

    stage_all(0, 0);
    __syncthreads();
    int cur = 0;

    for (int k0 = 0; k0 < K; k0 += BK) {
        if (k0 + BK < K) stage_all(cur ^ 1, k0 + BK);
        const u16* Ac = As[cur];
        const u16* Bc = Bs[cur];
        bf16x8 fa[FM], fb[FN], fal[FM], fbl[FN];
#pragma unroll
        for (int i = 0; i < FM; i++) {
            int a = swz((wr * WM + i * 16 + ro) * 64 + ko);
            fa[i] = *reinterpret_cast<const bf16x8*>((const char*)Ac + a);
            if (SPLIT)
                fal[i] = *reinterpret_cast<const bf16x8*>((const char*)(Ac + TBM * BK) + a);
        }
#pragma unroll
        for (int j = 0; j < FN; j++) {
            int a = swz((wc * WN + j * 16 + ro) * 64 + ko);
            fb[j] = *reinterpret_cast<const bf16x8*>((const char*)Bc + a);
            if (SPLIT)
                fbl[j] = *reinterpret_cast<const bf16x8*>((const char*)(Bc + TBN * BK) + a);
        }
#pragma unroll
        for (int i = 0; i < FM; i++)
#pragma unroll
            for (int j = 0; j < FN; j++) {
                acc[i][j] = __builtin_amdgcn_mfma_f32_16x16x32_bf16(fa[i], fb[j],
                                                                    acc[i][j], 0, 0, 0);
                if (SPLIT) {
                    acc[i][j] = __builtin_amdgcn_mfma_f32_16x16x32_bf16(fa[i], fbl[j],
                                                                        acc[i][j], 0, 0, 0);
                    acc[i][j] = __builtin_amdgcn_mfma_f32_16x16x32_bf16(fal[i], fb[j],
                                                                        acc[i][j], 0, 0, 0);
                }
            }
        __syncthreads();
        cur ^= 1;
    }

#pragma unroll
    for (int i = 0; i < FM; i++)
#pragma unroll
        for (int j = 0; j < FN; j++) {
            int col = n0 + wc * WN + j * 16 + (lane & 15);
            int rbase = m0 + wr * WM + i * 16 + (lane >> 4) * 4;
#pragma unroll
            for (int r = 0; r < 4; r++) {
                size_t off = (size_t)(rbase + r) * N + col;
                ((float*)Cout)[off] = acc[i][j][r];
            }
        }
}

// ---- 8-phase 256x256 GEMM (T3+T4+T5): counted-vmcnt pipeline ----
// 8 waves (2M x 4N), BK=64, LDS 128KB: A/B = [2 buf][2 half][128 rows x 128B].
// Wave output 128x64 spans both M-halves (rows wr*64 within each half), so
// each phase quadrant (qm,qn) is uniform across waves. Per K-tile u, 4 phases
// R=0..3 = quadrant (R>>1, R&1). Stage schedule (issue AFTER ds-reads, before
// barrier): R0: B1(u+1), R1: A1(u+1), R2: A0(u+2), R3: B0(u+2); vmcnt(4) only
// at R3 (vmcnt(0) at u==NT-2 to drain the tail). Raw s_barrier (no implicit
// vmcnt(0) drain) is what lets the 2 in-flight half-tiles span barriers.
// LDS swizzle for 128B rows: byte ^= ((row&7)<<4), both sides (pre-swizzled
// global source + swizzled ds_read) -> uniform 32-bank coverage.
template <int EPI, int KCHUNKS>
__global__ __launch_bounds__(512, 1) void gemm8(
    const u16* __restrict__ A, const u16* __restrict__ B,
    void* __restrict__ Cout,
    float* __restrict__ P1, float* __restrict__ P2, float* __restrict__ P3,
    const float* __restrict__ ext, int M, int N, int K) {
    __shared__ u16 As[2][2][128 * 64];
    __shared__ u16 Bs[2][2][128 * 64];
    const int t = threadIdx.x;
    const int lane = t & 63;
    const int wave = t >> 6;
    const int wr = wave >> 2, wc = wave & 3;   // 2M x 4N waves
    const int ro = lane & 15;
    const int ko = (lane >> 4) * 16;

    int bx = blockIdx.x, by = blockIdx.y;
    {   // XCD-aware bijective remap (grid x*y divisible by 8)
        int gx = gridDim.x;
        int n = gx * gridDim.y;
        int bid = by * gx + bx;
        int q = n >> 3;
        bid = (bid & 7) * q + (bid >> 3);
        bx = bid % gx; by = bid / gx;
    }
    const int m0 = by * 256, n0 = bx * 256;
    const int klen = K / KCHUNKS;
    const int z = (KCHUNKS > 1) ? blockIdx.z : 0;
    const int koff = z * klen;
    const int NT = klen / 64;

    const size_t krowB = (size_t)K * 2;
    const u16* A0p = A + (size_t)m0 * K;
    const u16* A1p = A + (size_t)(m0 + 128) * K;
    const u16* B0p = B + (size_t)n0 * K;
    const u16* B1p = B + (size_t)(n0 + 128) * K;

    f32x4 acc[8][4];
#pragma unroll
    for (int i = 0; i < 8; i++)
#pragma unroll
        for (int j = 0; j < 4; j++) acc[i][j] = (f32x4){0.f, 0.f, 0.f, 0.f};

    auto stage = [&](const u16* gbase, int kelem, u16* lds) {
#pragma unroll
        for (int rnd = 0; rnd < 2; rnd++) {
            int o = t * 16 + rnd * 8192;
            int os = o ^ (((o >> 7) & 7) << 4);
            int row = o >> 7, kb = os & 127;
            gload16((const char*)gbase + (size_t)row * krowB + (size_t)kelem * 2 + kb,
                    (char*)lds + o);
        }
    };

    // prologue: K-tile 0 (all 4 halves), then A0/B0 of K-tile 1
    stage(A0p, koff, As[0][0]);
    stage(B0p, koff, Bs[0][0]);
    stage(B1p, koff, Bs[0][1]);
    stage(A1p, koff, As[0][1]);
    stage(A0p, koff + 64, As[1][0]);
    stage(B0p, koff + 64, Bs[1][0]);
    asm volatile("s_waitcnt vmcnt(4)" ::: "memory");   // K-tile 0 landed
    asm volatile("s_barrier" ::: "memory");

#define PHASE(R)                                                               \
    {                                                                          \
        const int qm = (R) >> 1, qn = (R) & 1;                                 \
        const u16* Ah = As[u & 1][qm];                                         \
        const u16* Bh = Bs[u & 1][qn];                                         \
        bf16x8 fa[4][2], fb[2][2];                                             \
        _Pragma("unroll") for (int i = 0; i < 4; i++) {                        \
            int hr = wr * 64 + i * 16 + ro;                                    \
            int sw = (hr & 7) << 4;                                            \
            _Pragma("unroll") for (int kk = 0; kk < 2; kk++)                   \
                fa[i][kk] = *reinterpret_cast<const bf16x8*>(                  \
                    (const char*)Ah + ((hr * 128 + kk * 64 + ko) ^ sw));       \
        }                                                                      \
        _Pragma("unroll") for (int j = 0; j < 2; j++) {                        \
            int hr = wc * 32 + j * 16 + ro;                                    \
            int sw = (hr & 7) << 4;                                            \
            _Pragma("unroll") for (int kk = 0; kk < 2; kk++)                   \
                fb[j][kk] = *reinterpret_cast<const bf16x8*>(                  \
                    (const char*)Bh + ((hr * 128 + kk * 64 + ko) ^ sw));       \
        }                                                                      \
        if ((R) == 0 && u + 1 < NT) stage(B1p, koff + (u + 1) * 64, Bs[(u + 1) & 1][1]); \
        if ((R) == 1 && u + 1 < NT) stage(A1p, koff + (u + 1) * 64, As[(u + 1) & 1][1]); \
        if ((R) == 2 && u + 2 < NT) stage(A0p, koff + (u + 2) * 64, As[u & 1][0]);       \
        if ((R) == 3 && u + 2 < NT) stage(B0p, koff + (u + 2) * 64, Bs[u & 1][0]);       \
        asm volatile("s_barrier" ::: "memory");                                \
        __builtin_amdgcn_s_setprio(1);                                         \
        _Pragma("unroll") for (int i = 0; i < 4; i++)                          \
            _Pragma("unroll") for (int j = 0; j < 2; j++)                      \
                _Pragma("unroll") for (int kk = 0; kk < 2; kk++)               \
                    acc[qm * 4 + i][qn * 2 + j] =                              \
                        __builtin_amdgcn_mfma_f32_16x16x32_bf16(               \
                            fa[i][kk], fb[j][kk], acc[qm * 4 + i][qn * 2 + j], \
                            0, 0, 0);                                          \
        __builtin_amdgcn_s_setprio(0);                                         \
        if ((R) == 3) {                                                        \
            if (u == NT - 2)                                                   \
                asm volatile("s_waitcnt vmcnt(0)" ::: "memory");               \
            else                                                               \
                asm volatile("s_waitcnt vmcnt(4)" ::: "memory");               \
        }                                                                      \
        asm volatile("s_barrier" ::: "memory");                                \
    }

    for (int u = 0; u < NT; ++u) {
        PHASE(0)
        PHASE(1)
        PHASE(2)
        PHASE(3)
    }
#undef PHASE

    // epilogue
#pragma unroll
    for (int qi = 0; qi < 8; qi++) {
#pragma unroll
        for (int qj = 0; qj < 4; qj++) {
            const int qm = qi >> 2, i = qi & 3;
            const int qn = qj >> 1, j = qj & 1;
            int row0 = m0 + qm * 128 + wr * 64 + i * 16 + (lane >> 4) * 4;
            int col = n0 + qn * 128 + wc * 32 + j * 16 + ro;
#pragma unroll
            for (int r = 0; r < 4; r++) {
                float v = acc[qi][qj][r];
                size_t off = (size_t)(row0 + r) * N + col;
                if (EPI == 1) {
                    float s = v / (1.f + __expf(-v));
                    ((u16*)Cout)[off] = f2bf(s);
                } else {
                    if (z == 0)
                        ((float*)Cout)[off] = v + ext[off];
                    else {
                        float* P = (z == 1) ? P1 : (z == 2) ? P2 : P3;
                        P[off] = v;
                    }
                }
            }
        }
    }
}

// Rank of value v (lane l) among 64 values in LDS, JAX top_k tie order.
__device__ __forceinline__ int rank64(const float* base, float v, int l) {
    const float4* gv = reinterpret_cast<const float4*>(base);
    int rank = 0;
#pragma unroll
    for (int n = 0; n < 16; n++) {
        float4 o = gv[n];
        int b = n * 4;
        rank += (o.x > v) || (o.x == v && (b + 0) < l);
        rank += (o.y > v) || (o.y == v && (b + 1) < l);
        rank += (o.z > v) || (o.z == v && (b + 2) < l);
        rank += (o.w > v) || (o.w == v && (b + 3) < l);
    }
    return rank;
}

// Per-token router: loads precomputed sims (= hid @ Weff^T), rank-based
// top-8 per (p,h) group, rank-based cartesian top-8 per head, softmax gates.
__global__ __launch_bounds__(512) void router(
    const float* __restrict__ Simb,
    int* __restrict__ sidx_g, float* __restrict__ gate_g) {
    __shared__ float sims[QDIM];
    __shared__ float topv[8][TOPK];
    __shared__ int topi[8][TOPK];
    __shared__ float pv[NHEADS][64];
    __shared__ float st8[NHEADS][TOPK];
    __shared__ int sid8[NHEADS][TOPK];

    const int tok = blockIdx.x;
    const int tid = threadIdx.x;
    const int w = tid >> 6, l = tid & 63;

    sims[tid] = Simb[(size_t)tok * QDIM + tid];
    __syncthreads();

    {
        float v = sims[w * 64 + l];
        int rank = rank64(sims + w * 64, v, l);
        if (rank < TOPK) { topv[w][rank] = v; topi[w][rank] = l; }
    }
    __syncthreads();

    if (w < NHEADS) {
        pv[w][l] = topv[w][l >> 3] + topv[4 + w][l & 7];
    }
    __syncthreads();

    if (w < NHEADS) {
        float v = pv[w][l];
        int rank = rank64(pv[w], v, l);
        if (rank < TOPK) {
            st8[w][rank] = v;
            sid8[w][rank] = topi[w][l >> 3] * NKEYS + topi[4 + w][l & 7];
        }
    }
    __syncthreads();

    if (tid < NHEADS * TOPK) {
        int h = tid >> 3, r = tid & 7;
        float m0 = st8[h][0];
        float s = 0.f;
#pragma unroll
        for (int i = 0; i < TOPK; i++) s += __expf(st8[h][i] - m0);
        size_t o = ((size_t)tok * NHEADS + h) * TOPK + r;
        sidx_g[o] = sid8[h][r];
        gate_g[o] = __expf(st8[h][r] - m0) / s;
    }
}

// Streaming expert gather, fp8-e4m3 tables: one token per 256-thread block.
__global__ __launch_bounds__(256) void expert_gather(
    const u16* __restrict__ hid_bf, const u32* __restrict__ de_f8,
    const u32* __restrict__ ue_f8, const int* __restrict__ sidx_g,
    const float* __restrict__ gate_g, float* __restrict__ expst) {
    __shared__ float wks[32];
    __shared__ int eids_s[32];

    const int tok = blockIdx.x;
    const int w = threadIdx.x >> 6, l = threadIdx.x & 63;

    {   // dot phase
        u16x8 hv[2];
        const u16* hrow = hid_bf + (size_t)tok * HDIM + l * 16;
        hv[0] = *reinterpret_cast<const u16x8*>(hrow);
        hv[1] = *reinterpret_cast<const u16x8*>(hrow + 8);
        float h16[16];
#pragma unroll
        for (int t2 = 0; t2 < 8; t2++) { h16[t2] = bf2f(hv[0][t2]); h16[8 + t2] = bf2f(hv[1][t2]); }
        int eid[8];
        float gt[8];
#pragma unroll
        for (int j = 0; j < 8; j++) {
            size_t o = (size_t)tok * 32 + w * 8 + j;
            eid[j] = sidx_g[o];
            gt[j] = gate_g[o];
        }
        u32x4 dv[8];
#pragma unroll
        for (int j = 0; j < 8; j++) {
            const u32x4* dr = reinterpret_cast<const u32x4*>(de_f8 + (size_t)eid[j] * 256 + l * 4);
            dv[j] = *dr;
        }
        float dot[8];
#pragma unroll
        for (int j = 0; j < 8; j++) {
            float s = 0.f;
#pragma unroll
            for (int w2 = 0; w2 < 4; w2++) {
                u32 word = dv[j][w2];
                s += h16[w2 * 4 + 0] * __builtin_amdgcn_cvt_f32_fp8(word, 0);
                s += h16[w2 * 4 + 1] * __builtin_amdgcn_cvt_f32_fp8(word, 1);
                s += h16[w2 * 4 + 2] * __builtin_amdgcn_cvt_f32_fp8(word, 2);
                s += h16[w2 * 4 + 3] * __builtin_amdgcn_cvt_f32_fp8(word, 3);
            }
            dot[j] = s;
        }
#pragma unroll
        for (int m = 32; m; m >>= 1)
#pragma unroll
            for (int j = 0; j < 8; j++) dot[j] += __shfl_xor(dot[j], m, 64);
#pragma unroll
        for (int j = 0; j < 8; j++)
            if (l == j) {
                float x = dot[j] * gt[j];
                wks[w * 8 + j] = x / (1.f + __expf(-x));
                eids_s[w * 8 + j] = eid[j];
            }
    }
    __syncthreads();

    {   // acc phase: wave w owns dims [w*256, (w+1)*256); 4 fp8 per lane
        float acc0 = 0.f, acc1 = 0.f, acc2 = 0.f, acc3 = 0.f;
        const u32* ubase = ue_f8 + w * 64 + l;
#pragma unroll
        for (int m = 0; m < 32; m++) {
            int e = eids_s[m];
            float wk = wks[m];
            u32 u = ubase[(size_t)e * 256];
            acc0 += wk * __builtin_amdgcn_cvt_f32_fp8(u, 0);
            acc1 += wk * __builtin_amdgcn_cvt_f32_fp8(u, 1);
            acc2 += wk * __builtin_amdgcn_cvt_f32_fp8(u, 2);
            acc3 += wk * __builtin_amdgcn_cvt_f32_fp8(u, 3);
        }
        float4 a4 = make_float4(acc0, acc1, acc2, acc3);
        *reinterpret_cast<float4*>(expst + (size_t)tok * HDIM + w * 256 + l * 4) = a4;
    }
}

extern "C" void kernel_launch(void* const* d_in, const int* in_sizes, int n_in,
                              void* d_out, int out_size, void* d_ws, size_t ws_size,
                              hipStream_t stream) {
    const float* hidden = (const float*)d_in[0];
    const float* W_up = (const float*)d_in[1];
    const float* W_down = (const float*)d_in[2];
    const float* W_q = (const float*)d_in[3];
    const float* keys = (const float*)d_in[4];
    const float* down_embed = (const float*)d_in[5];
    const float* up_embed = (const float*)d_in[6];
    float* out = (float*)d_out;

    char* ws = (char*)d_ws;
    size_t off = 0;
    auto alloc = [&](size_t bytes) {
        void* p = ws + off;
        off += (bytes + 255) & ~(size_t)255;
        return p;
    };
    // Layout note: sizes are 256-multiples, so consecutive allocs are exactly
    // contiguous. Down-proj partials overlay regions dead by then:
    //   P1 = hid_hi+hid_lo (16.78MB), P2 = Simb+weff_hi+weff_lo+wup (first
    //   16.78MB of 18.87MB), P3 = fresh.
    u16* hid_hi = (u16*)alloc((size_t)TOKENS * HDIM * 2);
    u16* hid_lo = (u16*)alloc((size_t)TOKENS * HDIM * 2);
    float* Simb = (float*)alloc((size_t)TOKENS * QDIM * 4);
    u16* weff_hi = (u16*)alloc((size_t)QDIM * HDIM * 2);
    u16* weff_lo = (u16*)alloc((size_t)QDIM * HDIM * 2);
    u16* wup = (u16*)alloc((size_t)IDIM * HDIM * 2);
    u16* wdn = (u16*)alloc((size_t)HDIM * IDIM * 2);
    u16* act = (u16*)alloc((size_t)TOKENS * IDIM * 2);
    u32* de_f8 = (u32*)alloc((size_t)4096 * HDIM);
    u32* ue_f8 = (u32*)alloc((size_t)4096 * HDIM);
    float* expst = (float*)alloc((size_t)TOKENS * HDIM * 4);
    int* sidx_g = (int*)alloc((size_t)TOKENS * 32 * 4);
    float* gate_g = (float*)alloc((size_t)TOKENS * 32 * 4);
    float* P3 = (float*)alloc((size_t)TOKENS * HDIM * 4);
    float* P1 = (float*)hid_hi;
    float* P2 = (float*)Simb;

    cvt_all<<<(CVT_TOT + 255) / 256, 256, 0, stream>>>(
        hidden, W_up, W_down, down_embed, up_embed,
        hid_hi, hid_lo, wup, wdn, de_f8, ue_f8);
    weff_kernel<<<64, 256, 0, stream>>>(keys, W_q, weff_hi, weff_lo);

    // sim projection (q-proj with keys folded in), split-bf16, 64x128 tile
    gemm_bt<0, 64, 128, 2, 2, true>
        <<<dim3(QDIM / 128, TOKENS / 64), 256, 0, stream>>>(
        hid_hi, hid_lo, weff_hi, weff_lo, Simb, TOKENS, QDIM, HDIM);

    router<<<TOKENS, 512, 0, stream>>>(Simb, sidx_g, gate_g);
    expert_gather<<<TOKENS, 256, 0, stream>>>(hid_hi, de_f8, ue_f8, sidx_g, gate_g, expst);

    // up proj: 8-phase 256x256, grid (16,16)=256 blocks (1/CU)
    gemm8<1, 1><<<dim3(IDIM / 256, TOKENS / 256), 512, 0, stream>>>(
        hid_hi, wup, act, nullptr, nullptr, nullptr, nullptr, TOKENS, IDIM, HDIM);
    // down proj: 8-phase 256x256, K-split x4 -> grid (4,16,4)=256 blocks
    gemm8<2, 4><<<dim3(HDIM / 256, TOKENS / 256, 4), 512, 0, stream>>>(
        act, wdn, out, P1, P2, P3, expst, TOKENS, HDIM, IDIM);
    reduce_add3<<<(TOKENS * HDIM / 4 + 255) / 256, 256, 0, stream>>>(
        out, P1, P2, P3, TOKENS * HDIM / 4);
}

// Round 11
// 217.016 us; speedup vs baseline: 1.1350x; 1.1350x over previous
//
#include <hip/hip_runtime.h>

typedef unsigned short u16;
typedef unsigned int u32;

#define TOKENS 4096   // B*T
#define HDIM 1024
#define IDIM 4096
#define NHEADS 4
#define NKEYS 64
#define TOPK 8
#define QDIM 512      // 2 * NHEADS * 64

typedef __bf16 bf16x8 __attribute__((ext_vector_type(8)));
typedef float  f32x4  __attribute__((ext_vector_type(4)));
typedef u16    u16x8  __attribute__((ext_vector_type(8)));
typedef u16    u16x4  __attribute__((ext_vector_type(4)));
typedef u32    u32x4  __attribute__((ext_vector_type(4)));

__device__ __forceinline__ u16 f2bf(float f) {
    u32 u = __float_as_uint(f);
    u += 0x7fffu + ((u >> 16) & 1u);   // RNE
    return (u16)(u >> 16);
}
__device__ __forceinline__ float bf2f(u16 h) { return __uint_as_float(((u32)h) << 16); }

// ---- fused fp32->bf16 / fp32->fp8 conversion over all tensors ----
#define H_N4   1048576   // TOKENS*HDIM/4   (hi+lo)
#define WUP_N4 1048576
#define WDN_N4 1048576
#define DE_N4  1048576
#define UE_N4  1048576
#define CVT_TOT (H_N4 + WUP_N4 + WDN_N4 + DE_N4 + UE_N4)

__device__ __forceinline__ void cvt1(const float* in, u16* hi, u16* lo, int i) {
    float4 v = reinterpret_cast<const float4*>(in)[i];
    float vf[4] = {v.x, v.y, v.z, v.w};
    ushort4 h;
    u16 hh[4];
#pragma unroll
    for (int j = 0; j < 4; j++) hh[j] = f2bf(vf[j]);
    h.x = hh[0]; h.y = hh[1]; h.z = hh[2]; h.w = hh[3];
    reinterpret_cast<ushort4*>(hi)[i] = h;
    if (lo) {
        ushort4 l4;
        u16 ll[4];
#pragma unroll
        for (int j = 0; j < 4; j++) ll[j] = f2bf(vf[j] - bf2f(hh[j]));
        l4.x = ll[0]; l4.y = ll[1]; l4.z = ll[2]; l4.w = ll[3];
        reinterpret_cast<ushort4*>(lo)[i] = l4;
    }
}

__device__ __forceinline__ void cvt1_f8(const float* in, u32* out8, int i) {
    float4 v = reinterpret_cast<const float4*>(in)[i];
    u32 w = __builtin_amdgcn_cvt_pk_fp8_f32(v.x, v.y, 0u, false);
    w = __builtin_amdgcn_cvt_pk_fp8_f32(v.z, v.w, w, true);
    out8[i] = w;
}

__global__ __launch_bounds__(256) void cvt_all(
    const float* __restrict__ hidden, const float* __restrict__ W_up,
    const float* __restrict__ W_down, const float* __restrict__ de,
    const float* __restrict__ ue,
    u16* __restrict__ hid_hi, u16* __restrict__ hid_lo,
    u16* __restrict__ wup, u16* __restrict__ wdn,
    u32* __restrict__ de_f8, u32* __restrict__ ue_f8) {
    int i = blockIdx.x * 256 + threadIdx.x;
    if (i >= CVT_TOT) return;
    if (i < H_N4) { cvt1(hidden, hid_hi, hid_lo, i); return; }
    i -= H_N4;
    if (i < WUP_N4) { cvt1(W_up, wup, nullptr, i); return; }
    i -= WUP_N4;
    if (i < WDN_N4) { cvt1(W_down, wdn, nullptr, i); return; }
    i -= WDN_N4;
    if (i < DE_N4) { cvt1_f8(de, de_f8, i); return; }
    i -= DE_N4;
    cvt1_f8(ue, ue_f8, i);
}

// Weff[(p*4+h)*64+k][d] = sum_n keys[h][k][p][n] * Wq[p*256+h*64+n][d],
// fp32 accumulate, split hi/lo bf16 output.
__global__ __launch_bounds__(256) void weff_kernel(
    const float* __restrict__ keys, const float* __restrict__ Wq,
    u16* __restrict__ weff_hi, u16* __restrict__ weff_lo) {
    __shared__ float kk[64][65];
    __shared__ float wq_s[64][128];

    const int g = blockIdx.x >> 3, ds = blockIdx.x & 7;
    const int p = g >> 2, h = g & 3;
    const int d0 = ds * 128;
    const int t = threadIdx.x;
    const int base = p * 256 + h * 64;

    {
        int k = t >> 2, part = t & 3;
        const float* krow = keys + (((size_t)(h * NKEYS + k) * 2 + p) * 64);
#pragma unroll
        for (int j = 0; j < 4; j++) {
            int n0 = part * 16 + j * 4;
            float4 v = *reinterpret_cast<const float4*>(krow + n0);
            kk[k][n0 + 0] = v.x; kk[k][n0 + 1] = v.y;
            kk[k][n0 + 2] = v.z; kk[k][n0 + 3] = v.w;
        }
    }
    {
        int n = t >> 2, dpart = t & 3;
        const float* wrow = Wq + (size_t)(base + n) * HDIM + d0;
#pragma unroll
        for (int j = 0; j < 8; j++) {
            int dd = dpart * 32 + j * 4;
            float4 v = *reinterpret_cast<const float4*>(wrow + dd);
            *reinterpret_cast<float4*>(&wq_s[n][dd]) = v;
        }
    }
    __syncthreads();

    const int k = t & 63, dq = t >> 6;
    float acc[32];
#pragma unroll
    for (int i = 0; i < 32; i++) acc[i] = 0.f;
    for (int n = 0; n < 64; n++) {
        float kv = kk[k][n];
        const float4* wrow = reinterpret_cast<const float4*>(&wq_s[n][dq * 32]);
#pragma unroll
        for (int j = 0; j < 8; j++) {
            float4 w4 = wrow[j];
            acc[j * 4 + 0] += kv * w4.x; acc[j * 4 + 1] += kv * w4.y;
            acc[j * 4 + 2] += kv * w4.z; acc[j * 4 + 3] += kv * w4.w;
        }
    }
    size_t ro = (size_t)(g * 64 + k) * HDIM + d0 + dq * 32;
#pragma unroll
    for (int j = 0; j < 8; j++) {
        ushort4 hh, ll;
        u16 hv[4], lv[4];
#pragma unroll
        for (int i = 0; i < 4; i++) {
            float a = acc[j * 4 + i];
            hv[i] = f2bf(a);
            lv[i] = f2bf(a - bf2f(hv[i]));
        }
        hh.x = hv[0]; hh.y = hv[1]; hh.z = hv[2]; hh.w = hv[3];
        ll.x = lv[0]; ll.y = lv[1]; ll.z = lv[2]; ll.w = lv[3];
        *reinterpret_cast<ushort4*>(weff_hi + ro + j * 4) = hh;
        *reinterpret_cast<ushort4*>(weff_lo + ro + j * 4) = ll;
    }
}

// out += partial (after both K-chunks of down proj completed)
__global__ __launch_bounds__(256) void reduce_add(float* __restrict__ out,
                                                  const float* __restrict__ p, int n4) {
    int i = blockIdx.x * 256 + threadIdx.x;
    if (i >= n4) return;
    float4 a = reinterpret_cast<const float4*>(out)[i];
    float4 b = reinterpret_cast<const float4*>(p)[i];
    a.x += b.x; a.y += b.y; a.z += b.z; a.w += b.w;
    reinterpret_cast<float4*>(out)[i] = a;
}

__device__ __forceinline__ void gload16(const void* g, void* s) {
    auto gp = reinterpret_cast<const __attribute__((address_space(1))) u32*>(
        reinterpret_cast<uintptr_t>(g));
    auto sp = reinterpret_cast<__attribute__((address_space(3))) u32*>(
        reinterpret_cast<uintptr_t>(s));
    __builtin_amdgcn_global_load_lds(gp, sp, 16, 0, 0);
}

#define BK 32

// LDS rows of 64B; swizzle slot ^= (row>>1)&3 (verified: 0 bank conflicts).
__device__ __forceinline__ int swz(int a) { return a ^ (((a >> 7) & 3) << 4); }

template <int ROWS, int THREADS>
__device__ __forceinline__ void stage_tile(const u16* g, size_t krow_b, size_t kb0,
                                           u16* s, int t) {
#pragma unroll
    for (int rnd = 0; rnd < ROWS * 64 / (THREADS * 16); rnd++) {
        int o = t * 16 + rnd * THREADS * 16;
        int os = swz(o);
        int row = o >> 6, kb = os & 63;
        gload16((const char*)g + (size_t)row * krow_b + kb0 + kb, (char*)s + o);
    }
}

template <int N>
__device__ __forceinline__ void vm_wait() {
    if constexpr (N == 0) asm volatile("s_waitcnt vmcnt(0)" ::: "memory");
    else if constexpr (N == 2) asm volatile("s_waitcnt vmcnt(2)" ::: "memory");
    else if constexpr (N == 3) asm volatile("s_waitcnt vmcnt(3)" ::: "memory");
    else if constexpr (N == 4) asm volatile("s_waitcnt vmcnt(4)" ::: "memory");
    else if constexpr (N == 6) asm volatile("s_waitcnt vmcnt(6)" ::: "memory");
    else if constexpr (N == 8) asm volatile("s_waitcnt vmcnt(8)" ::: "memory");
    else static_assert(N == 0, "unsupported vmcnt");
}

// ---- 2-phase template (sim projection, SPLIT path) ----
template <int EPI, int TBM, int TBN, int WVM, int WVN, bool SPLIT>
__global__ __launch_bounds__(WVM * WVN * 64) void gemm_bt(
    const u16* __restrict__ A, const u16* __restrict__ Alo,
    const u16* __restrict__ B, const u16* __restrict__ Blo,
    void* __restrict__ Cout, int M, int N, int K) {
    constexpr int THREADS = WVM * WVN * 64;
    constexpr int NS = SPLIT ? 2 : 1;
    constexpr int WM = TBM / WVM, WN = TBN / WVN;
    constexpr int FM = WM / 16, FN = WN / 16;
    constexpr int ASZ = NS * TBM * BK;
    constexpr int BSZ = NS * TBN * BK;
    __shared__ u16 As[2][ASZ];
    __shared__ u16 Bs[2][BSZ];
    const int t = threadIdx.x;
    const int lane = t & 63;
    const int wave = t >> 6;
    const int wr = wave / WVN, wc = wave % WVN;
    const int m0 = blockIdx.y * TBM;
    const int n0 = blockIdx.x * TBN;

    f32x4 acc[FM][FN];
#pragma unroll
    for (int i = 0; i < FM; i++)
#pragma unroll
        for (int j = 0; j < FN; j++) acc[i][j] = (f32x4){0.f, 0.f, 0.f, 0.f};

    const size_t krow = (size_t)K * 2;
    const int ro = lane & 15;
    const int ko = (lane >> 4) * 16;

    const u16* Ab = A + (size_t)m0 * K;
    const u16* Bb = B + (size_t)n0 * K;
    const u16* Alb = SPLIT ? Alo + (size_t)m0 * K : nullptr;
    const u16* Blb = SPLIT ? Blo + (size_t)n0 * K : nullptr;

    auto stage_all = [&](int b, int k0) {
        size_t kb0 = (size_t)k0 * 2;
        stage_tile<TBM, THREADS>(Ab, krow, kb0, As[b], t);
        stage_tile<TBN, THREADS>(Bb, krow, kb0, Bs[b], t);
        if (SPLIT) {
            stage_tile<TBM, THREADS>(Alb, krow, kb0, As[b] + TBM * BK, t);
            stage_tile<TBN, THREADS>(Blb, krow, kb0, Bs[b] + TBN * BK, t);
        }
    };

    stage_all(0, 0);
    __syncthreads();
    int cur = 0;

    for (int k0 = 0; k0 < K; k0 += BK) {
        if (k0 + BK < K) stage_all(cur ^ 1, k0 + BK);
        const u16* Ac = As[cur];
        const u16* Bc = Bs[cur];
        bf16x8 fa[FM], fb[FN], fal[FM], fbl[FN];
#pragma unroll
        for (int i = 0; i < FM; i++) {
            int a = swz((wr * WM + i * 16 + ro) * 64 + ko);
            fa[i] = *reinterpret_cast<const bf16x8*>((const char*)Ac + a);
            if (SPLIT)
                fal[i] = *reinterpret_cast<const bf16x8*>((const char*)(Ac + TBM * BK) + a);
        }
#pragma unroll
        for (int j = 0; j < FN; j++) {
            int a = swz((wc * WN + j * 16 + ro) * 64 + ko);
            fb[j] = *reinterpret_cast<const bf16x8*>((const char*)Bc + a);
            if (SPLIT)
                fbl[j] = *reinterpret_cast<const bf16x8*>((const char*)(Bc + TBN * BK) + a);
        }
#pragma unroll
        for (int i = 0; i < FM; i++)
#pragma unroll
            for (int j = 0; j < FN; j++) {
                acc[i][j] = __builtin_amdgcn_mfma_f32_16x16x32_bf16(fa[i], fb[j],
                                                                    acc[i][j], 0, 0, 0);
                if (SPLIT) {
                    acc[i][j] = __builtin_amdgcn_mfma_f32_16x16x32_bf16(fa[i], fbl[j],
                                                                        acc[i][j], 0, 0, 0);
                    acc[i][j] = __builtin_amdgcn_mfma_f32_16x16x32_bf16(fal[i], fb[j],
                                                                        acc[i][j], 0, 0, 0);
                }
            }
        __syncthreads();
        cur ^= 1;
    }

#pragma unroll
    for (int i = 0; i < FM; i++)
#pragma unroll
        for (int j = 0; j < FN; j++) {
            int col = n0 + wc * WN + j * 16 + (lane & 15);
            int rbase = m0 + wr * WM + i * 16 + (lane >> 4) * 4;
#pragma unroll
            for (int r = 0; r < 4; r++) {
                size_t off = (size_t)(rbase + r) * N + col;
                ((float*)Cout)[off] = acc[i][j][r];
            }
        }
}

// ---- 3-stage-ring counted-vmcnt GEMM (T4 without the occupancy cost) ----
// Proven 2-phase body (64B rows, verified swizzle) + 3-deep LDS ring.
// Per iter u: issue stage(u+2) early -> vmcnt(2L) (tile u landed, 2 tiles
// stay in flight ACROSS barriers) -> s_barrier -> ds_read+MFMA buf[u%3] ->
// s_barrier. Raw s_barrier (no implicit vmcnt(0) drain) is the point.
// Hazards: stage(u+2) overwrites buf[(u-1)%3] -- guarded by prev iter's end
// barrier (all waves' reads of that buf were consumed by their MFMAs before
// they reached it). Reads of buf[u%3] complete before any wave reaches this
// iter's end barrier (MFMA operands force the lgkm wait).
template <int EPI, int TBM, int TBN, int WVM, int WVN, int KCHUNKS, bool XSWZ>
__global__ __launch_bounds__(WVM * WVN * 64) void gemm_p3(
    const u16* __restrict__ A, const u16* __restrict__ B,
    void* __restrict__ Cout, void* __restrict__ Cout2,
    const float* __restrict__ ext, int M, int N, int K) {
    constexpr int THREADS = WVM * WVN * 64;
    constexpr int WM = TBM / WVM, WN = TBN / WVN;
    constexpr int FM = WM / 16, FN = WN / 16;
    constexpr int LPS = (TBM + TBN) * 64 / (THREADS * 16);  // loads/thread/stage
    __shared__ u16 As[3][TBM * BK];
    __shared__ u16 Bs[3][TBN * BK];
    const int t = threadIdx.x;
    const int lane = t & 63;
    const int wave = t >> 6;
    const int wr = wave / WVN, wc = wave % WVN;
    const int ro = lane & 15;
    const int ko = (lane >> 4) * 16;

    int bx = blockIdx.x, by = blockIdx.y;
    if (XSWZ) {
        int gx = gridDim.x;
        int n = gx * gridDim.y;      // divisible by 8
        int bid = by * gx + bx;
        int q = n >> 3;
        bid = (bid & 7) * q + (bid >> 3);
        bx = bid % gx; by = bid / gx;
    }
    const int m0 = by * TBM;
    const int n0 = bx * TBN;
    const int klen = K / KCHUNKS;
    const int z = (KCHUNKS > 1) ? blockIdx.z : 0;
    const int koff = z * klen;
    const int NU = klen / BK;

    f32x4 acc[FM][FN];
#pragma unroll
    for (int i = 0; i < FM; i++)
#pragma unroll
        for (int j = 0; j < FN; j++) acc[i][j] = (f32x4){0.f, 0.f, 0.f, 0.f};

    const size_t krow = (size_t)K * 2;
    const u16* Ab = A + (size_t)m0 * K;
    const u16* Bb = B + (size_t)n0 * K;

    auto stage_all = [&](int b, int k0) {
        size_t kb0 = (size_t)k0 * 2;
        stage_tile<TBM, THREADS>(Ab, krow, kb0, As[b], t);
        stage_tile<TBN, THREADS>(Bb, krow, kb0, Bs[b], t);
    };

    stage_all(0, koff);
    stage_all(1, koff + BK);

    int cur = 0, pre = 2;   // buf indices: compute cur, stage into pre
    for (int u = 0; u < NU; ++u) {
        int k0 = koff + u * BK;
        if (u + 2 < NU) stage_all(pre, k0 + 2 * BK);
        if (u + 2 < NU) vm_wait<2 * LPS>();
        else if (u + 1 < NU) vm_wait<LPS>();
        else vm_wait<0>();
        __builtin_amdgcn_s_barrier();

        const u16* Ac = As[cur];
        const u16* Bc = Bs[cur];
        bf16x8 fa[FM], fb[FN];
#pragma unroll
        for (int i = 0; i < FM; i++) {
            int a = swz((wr * WM + i * 16 + ro) * 64 + ko);
            fa[i] = *reinterpret_cast<const bf16x8*>((const char*)Ac + a);
        }
#pragma unroll
        for (int j = 0; j < FN; j++) {
            int a = swz((wc * WN + j * 16 + ro) * 64 + ko);
            fb[j] = *reinterpret_cast<const bf16x8*>((const char*)Bc + a);
        }
#pragma unroll
        for (int i = 0; i < FM; i++)
#pragma unroll
            for (int j = 0; j < FN; j++)
                acc[i][j] = __builtin_amdgcn_mfma_f32_16x16x32_bf16(fa[i], fb[j],
                                                                    acc[i][j], 0, 0, 0);
        __builtin_amdgcn_s_barrier();
        cur = (cur == 2) ? 0 : cur + 1;
        pre = (pre == 2) ? 0 : pre + 1;
    }

#pragma unroll
    for (int i = 0; i < FM; i++)
#pragma unroll
        for (int j = 0; j < FN; j++) {
            int col = n0 + wc * WN + j * 16 + ro;
            int rbase = m0 + wr * WM + i * 16 + (lane >> 4) * 4;
#pragma unroll
            for (int r = 0; r < 4; r++) {
                float v = acc[i][j][r];
                size_t off = (size_t)(rbase + r) * N + col;
                if (EPI == 1) {
                    float s = v / (1.f + __expf(-v));
                    ((u16*)Cout)[off] = f2bf(s);
                } else {
                    if (KCHUNKS == 1 || z == 0)
                        ((float*)Cout)[off] = v + ext[off];
                    else
                        ((float*)Cout2)[off] = v;
                }
            }
        }
}

// Rank of value v (lane l) among 64 values in LDS, JAX top_k tie order.
__device__ __forceinline__ int rank64(const float* base, float v, int l) {
    const float4* gv = reinterpret_cast<const float4*>(base);
    int rank = 0;
#pragma unroll
    for (int n = 0; n < 16; n++) {
        float4 o = gv[n];
        int b = n * 4;
        rank += (o.x > v) || (o.x == v && (b + 0) < l);
        rank += (o.y > v) || (o.y == v && (b + 1) < l);
        rank += (o.z > v) || (o.z == v && (b + 2) < l);
        rank += (o.w > v) || (o.w == v && (b + 3) < l);
    }
    return rank;
}

// Per-token router: loads precomputed sims (= hid @ Weff^T), rank-based
// top-8 per (p,h) group, rank-based cartesian top-8 per head, softmax gates.
__global__ __launch_bounds__(512) void router(
    const float* __restrict__ Simb,
    int* __restrict__ sidx_g, float* __restrict__ gate_g) {
    __shared__ float sims[QDIM];
    __shared__ float topv[8][TOPK];
    __shared__ int topi[8][TOPK];
    __shared__ float pv[NHEADS][64];
    __shared__ float st8[NHEADS][TOPK];
    __shared__ int sid8[NHEADS][TOPK];

    const int tok = blockIdx.x;
    const int tid = threadIdx.x;
    const int w = tid >> 6, l = tid & 63;

    sims[tid] = Simb[(size_t)tok * QDIM + tid];
    __syncthreads();

    {
        float v = sims[w * 64 + l];
        int rank = rank64(sims + w * 64, v, l);
        if (rank < TOPK) { topv[w][rank] = v; topi[w][rank] = l; }
    }
    __syncthreads();

    if (w < NHEADS) {
        pv[w][l] = topv[w][l >> 3] + topv[4 + w][l & 7];
    }
    __syncthreads();

    if (w < NHEADS) {
        float v = pv[w][l];
        int rank = rank64(pv[w], v, l);
        if (rank < TOPK) {
            st8[w][rank] = v;
            sid8[w][rank] = topi[w][l >> 3] * NKEYS + topi[4 + w][l & 7];
        }
    }
    __syncthreads();

    if (tid < NHEADS * TOPK) {
        int h = tid >> 3, r = tid & 7;
        float m0 = st8[h][0];
        float s = 0.f;
#pragma unroll
        for (int i = 0; i < TOPK; i++) s += __expf(st8[h][i] - m0);
        size_t o = ((size_t)tok * NHEADS + h) * TOPK + r;
        sidx_g[o] = sid8[h][r];
        gate_g[o] = __expf(st8[h][r] - m0) / s;
    }
}

// Streaming expert gather, fp8-e4m3 tables: one token per 256-thread block.
__global__ __launch_bounds__(256) void expert_gather(
    const u16* __restrict__ hid_bf, const u32* __restrict__ de_f8,
    const u32* __restrict__ ue_f8, const int* __restrict__ sidx_g,
    const float* __restrict__ gate_g, float* __restrict__ expst) {
    __shared__ float wks[32];
    __shared__ int eids_s[32];

    const int tok = blockIdx.x;
    const int w = threadIdx.x >> 6, l = threadIdx.x & 63;

    {   // dot phase
        u16x8 hv[2];
        const u16* hrow = hid_bf + (size_t)tok * HDIM + l * 16;
        hv[0] = *reinterpret_cast<const u16x8*>(hrow);
        hv[1] = *reinterpret_cast<const u16x8*>(hrow + 8);
        float h16[16];
#pragma unroll
        for (int t2 = 0; t2 < 8; t2++) { h16[t2] = bf2f(hv[0][t2]); h16[8 + t2] = bf2f(hv[1][t2]); }
        int eid[8];
        float gt[8];
#pragma unroll
        for (int j = 0; j < 8; j++) {
            size_t o = (size_t)tok * 32 + w * 8 + j;
            eid[j] = sidx_g[o];
            gt[j] = gate_g[o];
        }
        u32x4 dv[8];
#pragma unroll
        for (int j = 0; j < 8; j++) {
            const u32x4* dr = reinterpret_cast<const u32x4*>(de_f8 + (size_t)eid[j] * 256 + l * 4);
            dv[j] = *dr;
        }
        float dot[8];
#pragma unroll
        for (int j = 0; j < 8; j++) {
            float s = 0.f;
#pragma unroll
            for (int w2 = 0; w2 < 4; w2++) {
                u32 word = dv[j][w2];
                s += h16[w2 * 4 + 0] * __builtin_amdgcn_cvt_f32_fp8(word, 0);
                s += h16[w2 * 4 + 1] * __builtin_amdgcn_cvt_f32_fp8(word, 1);
                s += h16[w2 * 4 + 2] * __builtin_amdgcn_cvt_f32_fp8(word, 2);
                s += h16[w2 * 4 + 3] * __builtin_amdgcn_cvt_f32_fp8(word, 3);
            }
            dot[j] = s;
        }
#pragma unroll
        for (int m = 32; m; m >>= 1)
#pragma unroll
            for (int j = 0; j < 8; j++) dot[j] += __shfl_xor(dot[j], m, 64);
#pragma unroll
        for (int j = 0; j < 8; j++)
            if (l == j) {
                float x = dot[j] * gt[j];
                wks[w * 8 + j] = x / (1.f + __expf(-x));
                eids_s[w * 8 + j] = eid[j];
            }
    }
    __syncthreads();

    {   // acc phase: wave w owns dims [w*256, (w+1)*256); 4 fp8 per lane
        float acc0 = 0.f, acc1 = 0.f, acc2 = 0.f, acc3 = 0.f;
        const u32* ubase = ue_f8 + w * 64 + l;
#pragma unroll
        for (int m = 0; m < 32; m++) {
            int e = eids_s[m];
            float wk = wks[m];
            u32 u = ubase[(size_t)e * 256];
            acc0 += wk * __builtin_amdgcn_cvt_f32_fp8(u, 0);
            acc1 += wk * __builtin_amdgcn_cvt_f32_fp8(u, 1);
            acc2 += wk * __builtin_amdgcn_cvt_f32_fp8(u, 2);
            acc3 += wk * __builtin_amdgcn_cvt_f32_fp8(u, 3);
        }
        float4 a4 = make_float4(acc0, acc1, acc2, acc3);
        *reinterpret_cast<float4*>(expst + (size_t)tok * HDIM + w * 256 + l * 4) = a4;
    }
}

extern "C" void kernel_launch(void* const* d_in, const int* in_sizes, int n_in,
                              void* d_out, int out_size, void* d_ws, size_t ws_size,
                              hipStream_t stream) {
    const float* hidden = (const float*)d_in[0];
    const float* W_up = (const float*)d_in[1];
    const float* W_down = (const float*)d_in[2];
    const float* W_q = (const float*)d_in[3];
    const float* keys = (const float*)d_in[4];
    const float* down_embed = (const float*)d_in[5];
    const float* up_embed = (const float*)d_in[6];
    float* out = (float*)d_out;

    char* ws = (char*)d_ws;
    size_t off = 0;
    auto alloc = [&](size_t bytes) {
        void* p = ws + off;
        off += (bytes + 255) & ~(size_t)255;
        return p;
    };
    u16* hid_hi = (u16*)alloc((size_t)TOKENS * HDIM * 2);
    // hid_lo (8.39 MB) + Simb (8.39 MB) are dead after router; the down-proj
    // K-chunk-1 partial (16.78 MB) overlays them.
    u16* hid_lo = (u16*)alloc((size_t)TOKENS * HDIM * 2);
    float* Simb = (float*)alloc((size_t)TOKENS * QDIM * 4);
    float* partial = (float*)hid_lo;
    u16* weff_hi = (u16*)alloc((size_t)QDIM * HDIM * 2);
    u16* weff_lo = (u16*)alloc((size_t)QDIM * HDIM * 2);
    u16* wup = (u16*)alloc((size_t)IDIM * HDIM * 2);
    u16* wdn = (u16*)alloc((size_t)HDIM * IDIM * 2);
    u16* act = (u16*)alloc((size_t)TOKENS * IDIM * 2);
    u32* de_f8 = (u32*)alloc((size_t)4096 * HDIM);
    u32* ue_f8 = (u32*)alloc((size_t)4096 * HDIM);
    float* expst = (float*)alloc((size_t)TOKENS * HDIM * 4);
    int* sidx_g = (int*)alloc((size_t)TOKENS * 32 * 4);
    float* gate_g = (float*)alloc((size_t)TOKENS * 32 * 4);

    cvt_all<<<(CVT_TOT + 255) / 256, 256, 0, stream>>>(
        hidden, W_up, W_down, down_embed, up_embed,
        hid_hi, hid_lo, wup, wdn, de_f8, ue_f8);
    weff_kernel<<<64, 256, 0, stream>>>(keys, W_q, weff_hi, weff_lo);

    // sim projection (q-proj with keys folded in), split-bf16, 64x128 tile
    gemm_bt<0, 64, 128, 2, 2, true>
        <<<dim3(QDIM / 128, TOKENS / 64), 256, 0, stream>>>(
        hid_hi, hid_lo, weff_hi, weff_lo, Simb, TOKENS, QDIM, HDIM);

    router<<<TOKENS, 512, 0, stream>>>(Simb, sidx_g, gate_g);
    expert_gather<<<TOKENS, 256, 0, stream>>>(hid_hi, de_f8, ue_f8, sidx_g, gate_g, expst);

    // up proj: 256x128 tile, 8 waves, 3-ring counted-vmcnt, grid 512, XCD-swz
    gemm_p3<1, 256, 128, 4, 2, 1, true>
        <<<dim3(IDIM / 128, TOKENS / 256), 512, 0, stream>>>(
        hid_hi, wup, act, nullptr, nullptr, TOKENS, IDIM, HDIM);
    // down proj: 128x128 tile, 3-ring counted-vmcnt, K-split x2, XCD-swz
    gemm_p3<2, 128, 128, 2, 2, 2, true>
        <<<dim3(HDIM / 128, TOKENS / 128, 2), 256, 0, stream>>>(
        act, wdn, out, partial, expst, TOKENS, HDIM, IDIM);
    reduce_add<<<(TOKENS * HDIM / 4 + 255) / 256, 256, 0, stream>>>(out, partial,
                                                                    TOKENS * HDIM / 4);
}